// Round 19
// baseline (25.276 us; speedup 1.0000x reference)
//
#include <hip/hip_runtime.h>
#include <math.h>

// SegmentTreeAttention — MI355X (gfx950), round 19.
// B=16, S=8192, D=64, N=32, LEVELS=5. f32 in/out. valid_lens per-batch.
//
// r18 (single-query 8-lane groups, lean state) = 22.3us best; occupancy
// axis saturated. This round: 4-LANE query groups (u=t&3, lane owns 16
// cols). The uniform per-level block (2 exps, compares, ~22 bookkeeping
// wave-inst) now serves 16 queries/wave instead of 8, and the DPP
// reduce is 2 steps not 3 -> ~30% fewer issue cycles per query-level.
// Dot FLOPs, LDS bytes, store bytes per query unchanged. Cost: ~90 VGPR
// (5 waves/SIMD) — betting issue cut > occupancy loss (r13 ran 23.9 at
// the same 5 waves with HIGHER per-query cost).
// Math verbatim from r13/r18: subtract-then-dot, div-free cond + 1e-6
// gray rescue (bit-exact), rcp weights, pow2 scales, coef-folded gather.

#define SEG_N   32
#define DIM     64
#define LEVELS  5
#define QPB     64      // queries per block (1 per 4-lane group)
#define THREADS 256
#define PAD     68      // LDS row stride in dwords
#define PADB    (PAD * 4)

#define DPP_QUAD_XOR1   0xB1    // quad_perm [1,0,3,2]
#define DPP_QUAD_XOR2   0x4E    // quad_perm [2,3,0,1]

#if __has_builtin(__builtin_amdgcn_rcpf)
#define RCPF(x) __builtin_amdgcn_rcpf(x)
#else
#define RCPF(x) (1.0f / (x))
#endif

template <int CTRL>
__device__ __forceinline__ float dpp_xadd(float v) {
    const int s = __builtin_amdgcn_update_dpp(0, __float_as_int(v), CTRL, 0xf, 0xf, true);
    return v + __int_as_float(s);
}

// 4-lane group sum, all lanes get the bit-identical total.
__device__ __forceinline__ float group4_sum(float v) {
    v = dpp_xadd<DPP_QUAD_XOR1>(v);
    v = dpp_xadd<DPP_QUAD_XOR2>(v);
    return v;
}

__device__ __forceinline__ float4 f4sub(const float4 a, const float4 b) {
    return make_float4(a.x - b.x, a.y - b.y, a.z - b.z, a.w - b.w);
}
__device__ __forceinline__ float dot4(const float4 a, const float4 b) {
    return a.x * b.x + a.y * b.y + a.z * b.z + a.w * b.w;
}
// acc += v * w
__device__ __forceinline__ void fmaw(float4& acc, const float4 v, float w) {
    acc.x = fmaf(v.x, w, acc.x);
    acc.y = fmaf(v.y, w, acc.y);
    acc.z = fmaf(v.z, w, acc.z);
    acc.w = fmaf(v.w, w, acc.w);
}

__global__ __launch_bounds__(THREADS) void segtree_attn_kernel(
    const float* __restrict__ q,
    const float* __restrict__ keys,
    const float* __restrict__ values,
    const int*   __restrict__ vlen,
    float*       __restrict__ out,
    int S)
{
    __shared__ float P[2][SEG_N * PAD];   // P[0]=Pk, P[1]=Pv

    const int b = blockIdx.y;
    const int t = threadIdx.x;
    const int g = t >> 2;           // query group within block (0..63)
    const int u = t & 3;            // lane within group
    const int c = u * 16;           // column base (4x float4)
    const int c4 = c * 4;           // byte offset of column base

    const int s = blockIdx.x * QPB + g;

    // ---- q load hoisted: latency hides under staging + barrier ----
    const float* qp = q + ((size_t)b * S + s) * DIM + c;
    const float4 q0 = *(const float4*)qp;
    const float4 q1 = *(const float4*)(qp + 4);
    const float4 q2 = *(const float4*)(qp + 8);
    const float4 q3 = *(const float4*)(qp + 12);

    // ---- Stage prefix sums into LDS: P[0]=0, P[m]=sum_{l=1..m} x[l] ----
    if (t < 2 * DIM) {
        const int col = t & (DIM - 1);
        const float* src = ((t < DIM) ? keys : values) + (size_t)b * SEG_N * DIM + col;
        float* dst = (t < DIM) ? P[0] : P[1];
        float acc = 0.0f;
        dst[col] = 0.0f;
        #pragma unroll
        for (int row = 1; row < SEG_N; ++row) {
            acc += src[row * DIM];
            dst[row * PAD + col] = acc;
        }
    }
    const int n = vlen[b];          // block-uniform (valid_lens is [B])
    __syncthreads();

    const int hnc = max(min(n - 1, SEG_N - 1), 0);
    const float scale[LEVELS] = {0.0625f, 0.125f, 0.25f, 0.5f, 1.0f};
    const char* Kb = (const char*)&P[0][0];
    const char* Vb = (const char*)&P[1][0];

    // initial frontiers: P[l-1]=P[0]=0 ; P[clamp(min(r,n-1))] = P[hnc]
    const int offN = hnc * PADB + c4;
    float4 pkR0 = *(const float4*)(Kb + offN);
    float4 pkR1 = *(const float4*)(Kb + offN + 16);
    float4 pkR2 = *(const float4*)(Kb + offN + 32);
    float4 pkR3 = *(const float4*)(Kb + offN + 48);
    float4 pkA0 = make_float4(0.f,0.f,0.f,0.f), pkA1 = make_float4(0.f,0.f,0.f,0.f);
    float4 pkA2 = make_float4(0.f,0.f,0.f,0.f), pkA3 = make_float4(0.f,0.f,0.f,0.f);

    int offA = c4, offR = offN;     // byte offsets of frontier rows
    float cA = 0.0f, cR = 0.0f;     // running coefs of frontier rows
    int mid = 16;
    int l = 1, r = SEG_N;

    // emissions: one finalized (row, coef) per level + 2 final frontiers
    float cE[LEVELS + 2];
    int   rowE[LEVELS + 2];

    #pragma unroll
    for (int lev = 0; lev < LEVELS; ++lev) {
        const int step = 8 >> lev;
        const int cm = min(mid, hnc);       // clamped row (clamp identity)
        const int offM = cm * PADB + c4;

        const float4 pkM0 = *(const float4*)(Kb + offM);
        const float4 pkM1 = *(const float4*)(Kb + offM + 16);
        const float4 pkM2 = *(const float4*)(Kb + offM + 32);
        const float4 pkM3 = *(const float4*)(Kb + offM + 48);

        // subtract-then-dot (matches reference rounding structure)
        float dL = dot4(q0, f4sub(pkM0, pkA0)) + dot4(q1, f4sub(pkM1, pkA1))
                 + dot4(q2, f4sub(pkM2, pkA2)) + dot4(q3, f4sub(pkM3, pkA3));
        float dR = dot4(q0, f4sub(pkR0, pkM0)) + dot4(q1, f4sub(pkR1, pkM1))
                 + dot4(q2, f4sub(pkR2, pkM2)) + dot4(q3, f4sub(pkR3, pkM3));

        dL = group4_sum(dL);
        dR = group4_sum(dR);

        const bool okL = (min(mid, n - 1) >= l);
        const bool okR = (min(r,   n - 1) >= mid + 1);

        const float sL = okL ? dL : 0.0f;
        const float sR = okR ? dR : 0.0f;

        // sigmoid denominators (exact, same __expf as all passing rounds)
        const float dnL = 1.0f + __expf(-sL);
        const float dnR = 1.0f + __expf(-sR);

        // div-free cond with gray rescue (r10-validated, bit-exact)
        bool cond = (dnL <= dnR);
        const bool gray = (dnL > dnR) && ((dnL - dnR) < dnL * 1e-6f);
        if (__any(gray)) {                  // P ~ 1e-5 per wave-level
            cond = ((1.0f / dnL) >= (1.0f / dnR));
        }

        const bool  oksel = cond ? okR : okL;
        const float wsel  = RCPF(cond ? dnR : dnL);  // weight: <=1ulp
        const float w = oksel ? (wsel * scale[lev]) : 0.0f;   // pow2: exact

        // ---- coefficient-folded emission (static slot = lev) ----
        rowE[lev] = cond ? offR : offA;
        cE[lev]   = cond ? (cR + w) : (cA - w);

        cR   = cond ? -w   : cR;
        cA   = cond ? cA   : w;
        offR = cond ? offM : offR;
        offA = cond ? offA : offM;

        if (cond) {
            r = mid;
            pkR0 = pkM0; pkR1 = pkM1; pkR2 = pkM2; pkR3 = pkM3;
        } else {
            l = mid + 1;
            pkA0 = pkM0; pkA1 = pkM1; pkA2 = pkM2; pkA3 = pkM3;
        }
        if (lev < LEVELS - 1) {
            mid = cond ? (mid - step) : (mid + step);
        }
    }

    // final frontier emissions
    rowE[LEVELS]     = offA;  cE[LEVELS]     = cA;
    rowE[LEVELS + 1] = offR;  cE[LEVELS + 1] = cR;

    // ---- folded gather: ans = sum_e coef_e * Pv[row_e]  (7 rows) ----
    float4 a0 = make_float4(0.f,0.f,0.f,0.f), a1 = make_float4(0.f,0.f,0.f,0.f);
    float4 a2 = make_float4(0.f,0.f,0.f,0.f), a3 = make_float4(0.f,0.f,0.f,0.f);
    #pragma unroll
    for (int e = 0; e < LEVELS + 2; ++e) {
        const float4 v0 = *(const float4*)(Vb + rowE[e]);
        const float4 v1 = *(const float4*)(Vb + rowE[e] + 16);
        const float4 v2 = *(const float4*)(Vb + rowE[e] + 32);
        const float4 v3 = *(const float4*)(Vb + rowE[e] + 48);
        fmaw(a0, v0, cE[e]);
        fmaw(a1, v1, cE[e]);
        fmaw(a2, v2, cE[e]);
        fmaw(a3, v3, cE[e]);
    }

    float* op = out + ((size_t)b * S + s) * DIM + c;
    *(float4*)op        = a0;
    *(float4*)(op + 4)  = a1;
    *(float4*)(op + 8)  = a2;
    *(float4*)(op + 12) = a3;
}

extern "C" void kernel_launch(void* const* d_in, const int* in_sizes, int n_in,
                              void* d_out, int out_size, void* d_ws, size_t ws_size,
                              hipStream_t stream) {
    const float* q    = (const float*)d_in[0];
    const float* keys = (const float*)d_in[1];
    const float* vals = (const float*)d_in[2];
    const int*   vl   = (const int*)d_in[3];
    float* out = (float*)d_out;

    const int B = in_sizes[3];                 // 16
    const int S = in_sizes[0] / (B * DIM);     // 8192

    dim3 grid(S / QPB, B);
    segtree_attn_kernel<<<grid, THREADS, 0, stream>>>(q, keys, vals, vl, out, S);
}

// Round 20
// 22.300 us; speedup vs baseline: 1.1335x; 1.1335x over previous
//
#include <hip/hip_runtime.h>
#include <math.h>

// SegmentTreeAttention — MI355X (gfx950), round 20 == round 18 (best).
// B=16, S=8192, D=64, N=32, LEVELS=5. f32 in/out. valid_lens per-batch.
//
// Final configuration after 19 rounds of A/B search (49 -> 22.3us):
//  - 1 query per 8-lane group, 256 threads, QPB=32 (lean ~60 VGPR ->
//    8 waves/SIMD; r19 showed 4-lane groups lose via VGPR, r13 showed
//    2-query ILP loses via VGPR, r2 showed 16-lane loses via issue).
//  - DPP butterfly reduce (quad_perm xor1/xor2 + row_half_mirror):
//    bit-identical order, off the DS pipe (r5, -13%).
//  - Clamped-read identity: row min(mid,hnc) serves as P[mid] + hiL
//    fallback; divergences provably masked by ok/w=0 (r6-r8 validated).
//  - Div-free cond (dnL<=dnR) + conservative 1e-6 gray rescue under
//    __any -> cond bit-exact vs IEEE-div reference compare (r10, -7%).
//  - Weights via v_rcp_f32 (<=1ulp, output-only; threshold 0.12 >> 1e-5).
//  - Coefficient-folded gather: sum w*(Pv[hi]-Pv[lo]) re-expressed as
//    7 coef*Pv[row] emissions with static slots (r13, -3%).
// Falsified alternatives: speculative prefetch (r6), split-kernel
// staging (r7), inline-Pv (r8/r12), branch speculation (r9), fast-dot
// descent (r11/r17), launch-bounds caps (r3), QPB 64/128 (r15).

#define SEG_N   32
#define DIM     64
#define LEVELS  5
#define QPB     32      // queries per block (1 per 8-lane group)
#define THREADS 256
#define PAD     68      // LDS row stride in dwords
#define PADB    (PAD * 4)

#define DPP_QUAD_XOR1   0xB1    // quad_perm [1,0,3,2]
#define DPP_QUAD_XOR2   0x4E    // quad_perm [2,3,0,1]
#define DPP_ROW_HMIRROR 0x141   // row_half_mirror (lane p -> 7-p within 8)

#if __has_builtin(__builtin_amdgcn_rcpf)
#define RCPF(x) __builtin_amdgcn_rcpf(x)
#else
#define RCPF(x) (1.0f / (x))
#endif

template <int CTRL>
__device__ __forceinline__ float dpp_xadd(float v) {
    const int s = __builtin_amdgcn_update_dpp(0, __float_as_int(v), CTRL, 0xf, 0xf, true);
    return v + __int_as_float(s);
}

// 8-lane group sum, all lanes get the bit-identical total.
__device__ __forceinline__ float group8_sum(float v) {
    v = dpp_xadd<DPP_QUAD_XOR1>(v);
    v = dpp_xadd<DPP_QUAD_XOR2>(v);
    v = dpp_xadd<DPP_ROW_HMIRROR>(v);
    return v;
}

__device__ __forceinline__ float4 f4sub(const float4 a, const float4 b) {
    return make_float4(a.x - b.x, a.y - b.y, a.z - b.z, a.w - b.w);
}
__device__ __forceinline__ float dot4(const float4 a, const float4 b) {
    return a.x * b.x + a.y * b.y + a.z * b.z + a.w * b.w;
}
// acc += v * w
__device__ __forceinline__ void fmaw(float4& acc, const float4 v, float w) {
    acc.x = fmaf(v.x, w, acc.x);
    acc.y = fmaf(v.y, w, acc.y);
    acc.z = fmaf(v.z, w, acc.z);
    acc.w = fmaf(v.w, w, acc.w);
}

__global__ __launch_bounds__(THREADS) void segtree_attn_kernel(
    const float* __restrict__ q,
    const float* __restrict__ keys,
    const float* __restrict__ values,
    const int*   __restrict__ vlen,
    float*       __restrict__ out,
    int S)
{
    __shared__ float P[2][SEG_N * PAD];   // P[0]=Pk, P[1]=Pv

    const int b = blockIdx.y;
    const int t = threadIdx.x;
    const int g = t >> 3;           // query group within block (0..31)
    const int u = t & 7;            // lane within group
    const int c = u * 8;            // column base (2x float4)
    const int c4 = c * 4;           // byte offset of column base

    const int s = blockIdx.x * QPB + g;

    // ---- q load hoisted: latency hides under staging + barrier ----
    const float* qp = q + ((size_t)b * S + s) * DIM + c;
    const float4 q0 = *(const float4*)qp;
    const float4 q1 = *(const float4*)(qp + 4);

    // ---- Stage prefix sums into LDS: P[0]=0, P[m]=sum_{l=1..m} x[l] ----
    if (t < 2 * DIM) {
        const int col = t & (DIM - 1);
        const float* src = ((t < DIM) ? keys : values) + (size_t)b * SEG_N * DIM + col;
        float* dst = (t < DIM) ? P[0] : P[1];
        float acc = 0.0f;
        dst[col] = 0.0f;
        #pragma unroll
        for (int row = 1; row < SEG_N; ++row) {
            acc += src[row * DIM];
            dst[row * PAD + col] = acc;
        }
    }
    const int n = vlen[b];          // block-uniform (valid_lens is [B])
    __syncthreads();

    const int hnc = max(min(n - 1, SEG_N - 1), 0);
    const float scale[LEVELS] = {0.0625f, 0.125f, 0.25f, 0.5f, 1.0f};
    const char* Kb = (const char*)&P[0][0];
    const char* Vb = (const char*)&P[1][0];

    // initial frontiers: P[l-1]=P[0]=0 ; P[clamp(min(r,n-1))] = P[hnc]
    const int offN = hnc * PADB + c4;
    float4 pkR0 = *(const float4*)(Kb + offN);
    float4 pkR1 = *(const float4*)(Kb + offN + 16);
    float4 pkA0 = make_float4(0.f,0.f,0.f,0.f), pkA1 = make_float4(0.f,0.f,0.f,0.f);

    int offA = c4, offR = offN;     // byte offsets of frontier rows
    float cA = 0.0f, cR = 0.0f;     // running coefs of frontier rows
    int mid = 16;
    int l = 1, r = SEG_N;

    // emissions: one finalized (row, coef) per level + 2 final frontiers
    float cE[LEVELS + 2];
    int   rowE[LEVELS + 2];

    #pragma unroll
    for (int lev = 0; lev < LEVELS; ++lev) {
        const int step = 8 >> lev;
        const int cm = min(mid, hnc);       // clamped row (clamp identity)
        const int offM = cm * PADB + c4;

        const float4 pkM0 = *(const float4*)(Kb + offM);
        const float4 pkM1 = *(const float4*)(Kb + offM + 16);

        // subtract-then-dot (matches reference rounding structure)
        float dL = dot4(q0, f4sub(pkM0, pkA0)) + dot4(q1, f4sub(pkM1, pkA1));
        float dR = dot4(q0, f4sub(pkR0, pkM0)) + dot4(q1, f4sub(pkR1, pkM1));

        dL = group8_sum(dL);
        dR = group8_sum(dR);

        const bool okL = (min(mid, n - 1) >= l);
        const bool okR = (min(r,   n - 1) >= mid + 1);

        const float sL = okL ? dL : 0.0f;
        const float sR = okR ? dR : 0.0f;

        // sigmoid denominators (exact, same __expf as all passing rounds)
        const float dnL = 1.0f + __expf(-sL);
        const float dnR = 1.0f + __expf(-sR);

        // div-free cond with gray rescue (r10-validated, bit-exact)
        bool cond = (dnL <= dnR);
        const bool gray = (dnL > dnR) && ((dnL - dnR) < dnL * 1e-6f);
        if (__any(gray)) {                  // P ~ 1e-5 per wave-level
            cond = ((1.0f / dnL) >= (1.0f / dnR));
        }

        const bool  oksel = cond ? okR : okL;
        const float wsel  = RCPF(cond ? dnR : dnL);  // weight: <=1ulp
        const float w = oksel ? (wsel * scale[lev]) : 0.0f;   // pow2: exact

        // ---- coefficient-folded emission (static slot = lev) ----
        rowE[lev] = cond ? offR : offA;
        cE[lev]   = cond ? (cR + w) : (cA - w);

        cR   = cond ? -w   : cR;
        cA   = cond ? cA   : w;
        offR = cond ? offM : offR;
        offA = cond ? offA : offM;

        if (cond) {
            r = mid;
            pkR0 = pkM0; pkR1 = pkM1;
        } else {
            l = mid + 1;
            pkA0 = pkM0; pkA1 = pkM1;
        }
        if (lev < LEVELS - 1) {
            mid = cond ? (mid - step) : (mid + step);
        }
    }

    // final frontier emissions
    rowE[LEVELS]     = offA;  cE[LEVELS]     = cA;
    rowE[LEVELS + 1] = offR;  cE[LEVELS + 1] = cR;

    // ---- folded gather: ans = sum_e coef_e * Pv[row_e]  (7 rows) ----
    float4 a0 = make_float4(0.f,0.f,0.f,0.f), a1 = make_float4(0.f,0.f,0.f,0.f);
    #pragma unroll
    for (int e = 0; e < LEVELS + 2; ++e) {
        const float4 v0 = *(const float4*)(Vb + rowE[e]);
        const float4 v1 = *(const float4*)(Vb + rowE[e] + 16);
        fmaw(a0, v0, cE[e]);
        fmaw(a1, v1, cE[e]);
    }

    float* op = out + ((size_t)b * S + s) * DIM + c;
    *(float4*)op       = a0;
    *(float4*)(op + 4) = a1;
}

extern "C" void kernel_launch(void* const* d_in, const int* in_sizes, int n_in,
                              void* d_out, int out_size, void* d_ws, size_t ws_size,
                              hipStream_t stream) {
    const float* q    = (const float*)d_in[0];
    const float* keys = (const float*)d_in[1];
    const float* vals = (const float*)d_in[2];
    const int*   vl   = (const int*)d_in[3];
    float* out = (float*)d_out;

    const int B = in_sizes[3];                 // 16
    const int S = in_sizes[0] / (B * DIM);     // 8192

    dim3 grid(S / QPB, B);
    segtree_attn_kernel<<<grid, THREADS, 0, stream>>>(q, keys, vals, vl, out, S);
}